// Round 9
// baseline (291.721 us; speedup 1.0000x reference)
//
#include <hip/hip_runtime.h>
#include <math.h>

#define Bg   32
#define NPGc 2048
#define Nn   (Bg*NPGc)      // 65536
#define DEGc 8
#define Ee   (Nn*DEGc)      // 524288
#define EPGc (NPGc*DEGc)    // 16384 edges per graph
#define INc  64
#define H1c  128
#define H2c  256
#define K1c  1024
#define K2c  512
#define N1c  (Bg*K1c)       // 32768
#define N2c  (Bg*K2c)       // 16384
#define SLAB 64             // fixed CSR slab per node

typedef __attribute__((ext_vector_type(8))) short short8;
typedef __attribute__((ext_vector_type(4))) float f32x4;

__device__ __forceinline__ ushort f2bf(float f) {
    uint u = __float_as_uint(f);
    uint r = (u + 0x7fffu + ((u >> 16) & 1u)) >> 16;
    return (ushort)r;
}
__device__ __forceinline__ float bfhi(uint v) { return __uint_as_float(v & 0xffff0000u); }
__device__ __forceinline__ float bflo(uint v) { return __uint_as_float(v << 16); }
__device__ __forceinline__ uint fkey(float f) {
    uint u = __float_as_uint(f);
    return u ^ ((uint)((int)u >> 31) | 0x80000000u);
}

// ---------------- prep: wt transpose + x->bf16 + inits ----------------
__global__ void prep_kernel(const float* __restrict__ x,
                            const float* __restrict__ W1l, const float* __restrict__ W1r,
                            const float* __restrict__ W2l, const float* __restrict__ W2r,
                            ushort* __restrict__ T1l, ushort* __restrict__ T1r,
                            ushort* __restrict__ T2l, ushort* __restrict__ T2r,
                            ushort* __restrict__ xb, int* __restrict__ wc1,
                            int* __restrict__ dstats, int* __restrict__ pooled) {
    int id = blockIdx.x * blockDim.x + threadIdx.x;
    if (id < 8192) {
        int c = id / 64, k = id % 64;
        T1l[id] = f2bf(W1l[k * 128 + c]);
        T1r[id] = f2bf(W1r[k * 128 + c]);
        return;
    }
    id -= 8192;
    if (id < 32768) {
        int c = id / 128, k = id % 128;
        T2l[id] = f2bf(W2l[k * 256 + c]);
        T2r[id] = f2bf(W2r[k * 256 + c]);
        return;
    }
    id -= 32768;
    if (id < 16384) { ((int4*)wc1)[id] = (int4){0, 0, 0, 0}; return; }
    id -= 16384;
    if (id < 384)   { ((int4*)dstats)[id] = (int4){0, 0, 0, 0}; return; }
    id -= 384;
    if (id < 2048)  { ((int4*)pooled)[id] = (int4){0, 0, 0, 0}; return; }
    id -= 2048;
    if (id < Nn * 64 / 4) {  // x -> bf16
        float4 v = ((const float4*)x)[id];
        ushort4 o; o.x = f2bf(v.x); o.y = f2bf(v.y); o.z = f2bf(v.z); o.w = f2bf(v.w);
        ((ushort4*)xb)[id] = o;
    }
}
#define PREP_TOTAL (8192 + 32768 + 16384 + 384 + 2048 + Nn*64/4)

// ---------------- self-counting fill into fixed slabs (wc = cursor -> degree) ---------------
__global__ void fill1_kernel(const int* __restrict__ src, const int* __restrict__ tgt,
                             int* __restrict__ wc1, int* __restrict__ col1) {
    int e = blockIdx.x * blockDim.x + threadIdx.x;
    if (e >= Ee) return;
    int t = tgt[e];
    int p = atomicAdd(&wc1[t], 1);
    col1[t * SLAB + p] = src[e];
}

// ---------------- mean aggregation: 16B/lane gathers, bf16, XCD-swizzled ----------------
__device__ __forceinline__ void acc8(float* a, uint4 v) {
    a[0] += bflo(v.x); a[1] += bfhi(v.x);
    a[2] += bflo(v.y); a[3] += bfhi(v.y);
    a[4] += bflo(v.z); a[5] += bfhi(v.z);
    a[6] += bflo(v.w); a[7] += bfhi(v.w);
}
__device__ __forceinline__ uint4 pack8(const float* a, float inv) {
    uint4 o;
    o.x = (uint)f2bf(a[0] * inv) | ((uint)f2bf(a[1] * inv) << 16);
    o.y = (uint)f2bf(a[2] * inv) | ((uint)f2bf(a[3] * inv) << 16);
    o.z = (uint)f2bf(a[4] * inv) | ((uint)f2bf(a[5] * inv) << 16);
    o.w = (uint)f2bf(a[6] * inv) | ((uint)f2bf(a[7] * inv) << 16);
    return o;
}

__global__ void agg1_kernel(const ushort* __restrict__ xb, const int* __restrict__ deg,
                            const int* __restrict__ col, ushort* __restrict__ out) {
    int b = blockIdx.x;
    int w = ((b & 7) << 8) + (b >> 3);
    int gid = w * 256 + threadIdx.x;
    int node = gid >> 3, ln = gid & 7;
    int bg = node * SLAB, dg = deg[node];
    float a[8] = {0.f, 0.f, 0.f, 0.f, 0.f, 0.f, 0.f, 0.f};
    for (int i = bg; i < bg + dg; i++)
        acc8(a, *(const uint4*)&xb[((size_t)col[i] << 6) + ln * 8]);
    int c = dg < 1 ? 1 : dg;
    *(uint4*)&out[((size_t)node << 6) + ln * 8] = pack8(a, 1.f / (float)c);
}

__global__ void agg2_kernel(const ushort* __restrict__ xb, const int* __restrict__ deg,
                            const int* __restrict__ col, ushort* __restrict__ out) {
    int b = blockIdx.x;
    int w = ((b & 7) << 8) + (b >> 3);
    int gid = w * 256 + threadIdx.x;
    int node = gid >> 4, ln = gid & 15;
    int bg = node * SLAB, dg = deg[node];
    float a[8] = {0.f, 0.f, 0.f, 0.f, 0.f, 0.f, 0.f, 0.f};
    for (int i = bg; i < bg + dg; i++)
        acc8(a, *(const uint4*)&xb[((size_t)col[i] << 7) + ln * 8]);
    int c = dg < 1 ? 1 : dg;
    *(uint4*)&out[((size_t)node << 7) + ln * 8] = pack8(a, 1.f / (float)c);
}

// ------- MFMA GEMM 128x64 tile + fused per-channel BN-stat partials (f64 atomics) -----------
template<int K, int COUT>
__global__ __launch_bounds__(256) void gemm_mfma_kernel(
        const ushort* __restrict__ Aagg, const ushort* __restrict__ Ax,
        const ushort* __restrict__ Wtl, const ushort* __restrict__ Wtr,
        const float* __restrict__ bias, float* __restrict__ out,
        double* __restrict__ dsum, double* __restrict__ dsq) {
    __shared__ ushort As[2][128][72];
    __shared__ ushort Bs[2][64][72];
    __shared__ float bsumS[2][64], bsqS[2][64];
    int m0 = blockIdx.x * 128;
    int c0 = blockIdx.y * 64;
    int lane = threadIdx.x & 63;
    int wid = threadIdx.x >> 6;
    int wr = (wid & 1) * 64, wc = (wid >> 1) * 32;
    int l16 = lane & 15, quad = lane >> 4;

    f32x4 acc[4][2];
#pragma unroll
    for (int a = 0; a < 4; a++)
#pragma unroll
        for (int b = 0; b < 2; b++) acc[a][b] = (f32x4){0.f, 0.f, 0.f, 0.f};

    for (int kk0 = 0; kk0 < K; kk0 += 64) {
        for (int idx = threadIdx.x; idx < 1024; idx += 256) {
            int r = idx >> 3, ck = (idx & 7) * 8;
            *(uint4*)&As[0][r][ck] = *(const uint4*)&Aagg[(size_t)(m0 + r) * K + kk0 + ck];
            *(uint4*)&As[1][r][ck] = *(const uint4*)&Ax[(size_t)(m0 + r) * K + kk0 + ck];
        }
        for (int idx = threadIdx.x; idx < 512; idx += 256) {
            int r = idx >> 3, ck = (idx & 7) * 8;
            *(uint4*)&Bs[0][r][ck] = *(const uint4*)&Wtl[(size_t)(c0 + r) * K + kk0 + ck];
            *(uint4*)&Bs[1][r][ck] = *(const uint4*)&Wtr[(size_t)(c0 + r) * K + kk0 + ck];
        }
        __syncthreads();
#pragma unroll
        for (int kk = 0; kk < 64; kk += 32) {
            short8 a[2][4], b[2][2];
#pragma unroll
            for (int s = 0; s < 2; s++)
#pragma unroll
                for (int mt = 0; mt < 4; mt++)
                    a[s][mt] = *(const short8*)&As[s][wr + mt * 16 + l16][kk + quad * 8];
#pragma unroll
            for (int s = 0; s < 2; s++)
#pragma unroll
                for (int nt = 0; nt < 2; nt++)
                    b[s][nt] = *(const short8*)&Bs[s][wc + nt * 16 + l16][kk + quad * 8];
#pragma unroll
            for (int mt = 0; mt < 4; mt++)
#pragma unroll
                for (int nt = 0; nt < 2; nt++) {
                    acc[mt][nt] = __builtin_amdgcn_mfma_f32_16x16x32_bf16(
                        a[0][mt], b[0][nt], acc[mt][nt], 0, 0, 0);
                    acc[mt][nt] = __builtin_amdgcn_mfma_f32_16x16x32_bf16(
                        a[1][mt], b[1][nt], acc[mt][nt], 0, 0, 0);
                }
        }
        __syncthreads();
    }
    float s[2] = {0.f, 0.f}, sq[2] = {0.f, 0.f};
#pragma unroll
    for (int nt = 0; nt < 2; nt++) {
        int col = c0 + wc + nt * 16 + l16;
        float bv = bias[col];
#pragma unroll
        for (int mt = 0; mt < 4; mt++)
#pragma unroll
            for (int r = 0; r < 4; r++) {
                int row = m0 + wr + mt * 16 + quad * 4 + r;
                float ov = acc[mt][nt][r] + bv;
                out[(size_t)row * COUT + col] = ov;
                s[nt] += ov; sq[nt] += ov * ov;
            }
    }
#pragma unroll
    for (int nt = 0; nt < 2; nt++) {
        float ss = s[nt], qq = sq[nt];
        ss += __shfl_down(ss, 16); qq += __shfl_down(qq, 16);
        ss += __shfl_down(ss, 32); qq += __shfl_down(qq, 32);
        if (quad == 0) {
            bsumS[wid & 1][wc + nt * 16 + l16] = ss;
            bsqS[wid & 1][wc + nt * 16 + l16] = qq;
        }
    }
    __syncthreads();
    if (threadIdx.x < 64) {
        int c = threadIdx.x;
        atomicAdd(&dsum[c0 + c], (double)(bsumS[0][c] + bsumS[1][c]));
        atomicAdd(&dsq[c0 + c], (double)(bsqS[0][c] + bsqS[1][c]));
    }
}

// ---------------- score dots from RAW h; scale/shift computed in-block ----------------
template<int C>
__global__ __launch_bounds__(256) void score_kernel(const float* __restrict__ h,
                                                    const double* __restrict__ dsum,
                                                    const double* __restrict__ dsq,
                                                    const float* __restrict__ g,
                                                    const float* __restrict__ b,
                                                    const float* __restrict__ wrel,
                                                    const float* __restrict__ wroot,
                                                    float* __restrict__ r,
                                                    float* __restrict__ root, int n) {
    __shared__ float sc[C], sh[C], wrl[C], wrt[C];
    if ((int)threadIdx.x < C) {
        int c = threadIdx.x;
        double m = dsum[c] / (double)n;
        double var = dsq[c] / (double)n - m * m;
        float s = g[c] * (float)(1.0 / sqrt(var + 1e-5));
        sc[c] = s; sh[c] = b[c] - (float)m * s;
        wrl[c] = wrel[c]; wrt[c] = wroot[c];
    }
    __syncthreads();
    int gid = blockIdx.x * 256 + threadIdx.x;
    int node = gid >> 6, lane = gid & 63;
    float rr = 0.f, rt = 0.f;
    for (int c = lane; c < C; c += 64) {
        float v = fmaxf(h[(size_t)node * C + c] * sc[c] + sh[c], 0.f);
        rr += v * wrl[c];
        rt += v * wrt[c];
    }
    for (int off = 32; off; off >>= 1) {
        rr += __shfl_down(rr, off);
        rt += __shfl_down(rt, off);
    }
    if (lane == 0) { r[node] = rr; root[node] = rt; }
}

// ------ topk1: edge-parallel score sum + radix select + LDS map + fused layer2 slab fill ----
__global__ void __launch_bounds__(1024) topk1_kernel(const float* __restrict__ r,
                                                     const float* __restrict__ root,
                                                     const int* __restrict__ src,
                                                     const int* __restrict__ tgt,
                                                     const float* __restrict__ brel,
                                                     int* __restrict__ perm,
                                                     float* __restrict__ tval,
                                                     int* __restrict__ wc2,
                                                     int* __restrict__ col2) {
    __shared__ float svals[2048];
    __shared__ int mapL[2048];
    __shared__ int wcL[1024];
    __shared__ uint hist[257];
    __shared__ uint wsum[16];
    __shared__ uint s_b, s_rem;
    int g = blockIdx.x;
    int tid = threadIdx.x;
    int lane = tid & 63, wid = tid >> 6;
    int base = g * NPGc;
    float bv = brel[0];
    // phase 0: init
    svals[tid] = bv + root[base + tid];
    svals[tid + 1024] = bv + root[base + tid + 1024];
    mapL[tid] = -1; mapL[tid + 1024] = -1;
    wcL[tid] = 0;
    if (tid == 256) hist[256] = 0;
    if (tid < 256) hist[tid] = 0;
    __syncthreads();
    // phase 1: edge-parallel score accumulation (LDS float atomics)
    for (int j = 0; j < EPGc / 1024; j++) {
        int e = g * EPGc + tid + (j << 10);
        atomicAdd(&svals[tgt[e] - base], r[src[e]]);
    }
    __syncthreads();
    // phase 2: 4x8-bit radix select (exact k-th largest)
    uint prefix = 0, himask = 0, rem = (uint)K1c;
    for (int shift = 24; shift >= 0; shift -= 8) {
        for (int i = tid; i < NPGc; i += 1024) {
            uint kk = fkey(svals[i]);
            if ((kk & himask) == prefix) atomicAdd(&hist[(kk >> shift) & 255], 1);
        }
        __syncthreads();
        if (tid < 64) {
            int L = tid;
            uint h0 = hist[4 * L], h1 = hist[4 * L + 1], h2 = hist[4 * L + 2],
                 h3 = hist[4 * L + 3];
            uint s3 = h3, s2 = h2 + s3, s1 = h1 + s2, s0 = h0 + s1;
            uint v = s0;
            for (int off = 1; off < 64; off <<= 1) {
                uint u = __shfl_down(v, off);
                if (L + off < 64) v += u;
            }
            uint above = v - s0;
            hist[4 * L] = s0 + above;
            hist[4 * L + 1] = s1 + above;
            hist[4 * L + 2] = s2 + above;
            hist[4 * L + 3] = s3 + above;
        }
        __syncthreads();
        if (tid < 256) {
            uint sb = hist[tid], sb1 = hist[tid + 1];
            if (sb >= rem && sb1 < rem) { s_b = (uint)tid; s_rem = rem - sb1; }
        }
        __syncthreads();
        prefix |= (s_b << shift);
        rem = s_rem;
        himask |= (0xFFu << shift);
        if (tid < 256) hist[tid] = 0;
        __syncthreads();
    }
    uint thr = prefix;
    uint m = rem;
    // phase 3: selection + compaction (interleaved), map into LDS
    uint gcnt = 0, ecnt = 0, gflags = 0, eflags = 0;
    for (int j = 0; j < 2; j++) {
        uint kk = fkey(svals[tid + (j << 10)]);
        if (kk > thr) { gflags |= 1u << j; gcnt++; }
        else if (kk == thr) { eflags |= 1u << j; ecnt++; }
    }
    uint key = (gcnt << 16) | ecnt;
    uint v = key;
    for (int off = 1; off < 64; off <<= 1) {
        uint u = __shfl_up(v, off);
        if (lane >= off) v += u;
    }
    if (lane == 63) wsum[wid] = v;
    __syncthreads();
    if (tid < 16) {
        uint w0 = wsum[tid], w = w0;
        for (int off = 1; off < 16; off <<= 1) {
            uint u = __shfl_up(w, off);
            if ((int)tid >= off) w += u;
        }
        wsum[tid] = w - w0;
    }
    __syncthreads();
    uint excl = (v - key) + wsum[wid];
    uint gbase = excl >> 16, ebase = excl & 0xFFFFu;
    for (int j = 0; j < 2; j++) {
        bool gt = (gflags >> j) & 1u;
        bool eq = (eflags >> j) & 1u;
        if (gt || (eq && ebase < m)) {
            uint pos = gbase + min(ebase, m);
            int i = tid + (j << 10);
            int o = g * K1c + (int)pos;
            perm[o] = base + i;
            tval[o] = tanhf(svals[i]);
            mapL[i] = o;
        }
        gbase += gt ? 1u : 0u;
        ebase += eq ? 1u : 0u;
    }
    __syncthreads();
    // phase 4: layer2 slab fill through LDS map
    int nbase = g * K1c;
    for (int j = 0; j < EPGc / 1024; j++) {
        int e = g * EPGc + tid + (j << 10);
        int ns = mapL[src[e] - base];
        int nt = mapL[tgt[e] - base];
        if (ns >= 0 && nt >= 0) {
            int p = atomicAdd(&wcL[nt - nbase], 1);
            col2[nt * SLAB + p] = ns;
        }
    }
    __syncthreads();
    // phase 5: write layer2 degrees
    wc2[nbase + tid] = wcL[tid];
}

// ---------------- topk2: serial slab score + radix select (no map/fill) ----------------
__global__ void __launch_bounds__(1024) topk2_kernel(const float* __restrict__ r,
                                                     const float* __restrict__ root,
                                                     const int* __restrict__ deg,
                                                     const int* __restrict__ col,
                                                     const float* __restrict__ brel,
                                                     int* __restrict__ perm,
                                                     float* __restrict__ tval) {
    __shared__ float svals[1024];
    __shared__ uint hist[257];
    __shared__ uint wsum[16];
    __shared__ uint s_b, s_rem;
    int g = blockIdx.x;
    int tid = threadIdx.x;
    int lane = tid & 63, wid = tid >> 6;
    float bv = brel[0];
    {
        int gi = g * K1c + tid;
        float acc = bv + root[gi];
        int e0 = gi * SLAB, e1 = e0 + deg[gi];
        for (int e = e0; e < e1; e++) acc += r[col[e]];
        svals[tid] = acc;
    }
    if (tid == 256) hist[256] = 0;
    if (tid < 256) hist[tid] = 0;
    __syncthreads();

    uint prefix = 0, himask = 0, rem = (uint)K2c;
    for (int shift = 24; shift >= 0; shift -= 8) {
        {
            uint kk = fkey(svals[tid]);
            if ((kk & himask) == prefix) atomicAdd(&hist[(kk >> shift) & 255], 1);
        }
        __syncthreads();
        if (tid < 64) {
            int L = tid;
            uint h0 = hist[4 * L], h1 = hist[4 * L + 1], h2 = hist[4 * L + 2],
                 h3 = hist[4 * L + 3];
            uint s3 = h3, s2 = h2 + s3, s1 = h1 + s2, s0 = h0 + s1;
            uint v = s0;
            for (int off = 1; off < 64; off <<= 1) {
                uint u = __shfl_down(v, off);
                if (L + off < 64) v += u;
            }
            uint above = v - s0;
            hist[4 * L] = s0 + above;
            hist[4 * L + 1] = s1 + above;
            hist[4 * L + 2] = s2 + above;
            hist[4 * L + 3] = s3 + above;
        }
        __syncthreads();
        if (tid < 256) {
            uint sb = hist[tid], sb1 = hist[tid + 1];
            if (sb >= rem && sb1 < rem) { s_b = (uint)tid; s_rem = rem - sb1; }
        }
        __syncthreads();
        prefix |= (s_b << shift);
        rem = s_rem;
        himask |= (0xFFu << shift);
        if (tid < 256) hist[tid] = 0;
        __syncthreads();
    }
    uint thr = prefix;
    uint m = rem;

    uint kk = fkey(svals[tid]);
    bool gt = kk > thr, eq = kk == thr;
    uint key = (gt ? 0x10000u : 0u) | (eq ? 1u : 0u);
    uint v = key;
    for (int off = 1; off < 64; off <<= 1) {
        uint u = __shfl_up(v, off);
        if (lane >= off) v += u;
    }
    if (lane == 63) wsum[wid] = v;
    __syncthreads();
    if (tid < 16) {
        uint w0 = wsum[tid], w = w0;
        for (int off = 1; off < 16; off <<= 1) {
            uint u = __shfl_up(w, off);
            if ((int)tid >= off) w += u;
        }
        wsum[tid] = w - w0;
    }
    __syncthreads();
    uint excl = (v - key) + wsum[wid];
    uint gbase = excl >> 16, ebase = excl & 0xFFFFu;
    if (gt || (eq && ebase < m)) {
        uint pos = gbase + min(ebase, m);
        int o = g * K2c + (int)pos;
        perm[o] = g * K1c + tid;
        tval[o] = tanhf(svals[tid]);
    }
}

// -------- gather1: BN-apply + tanh-scale gather h1 -> h1pb (bf16) --------
__global__ void __launch_bounds__(256) gather1_kernel(
        const float* __restrict__ h1, const int* __restrict__ perm1,
        const float* __restrict__ tv1, const double* __restrict__ dsum,
        const double* __restrict__ dsq, const float* __restrict__ g,
        const float* __restrict__ b, ushort* __restrict__ h1pb) {
    __shared__ float sc[128], sh[128];
    if (threadIdx.x < 128) {
        int c = threadIdx.x;
        double m = dsum[c] / (double)Nn;
        double var = dsq[c] / (double)Nn - m * m;
        float s = g[c] * (float)(1.0 / sqrt(var + 1e-5));
        sc[c] = s; sh[c] = b[c] - (float)m * s;
    }
    __syncthreads();
    int t = blockIdx.x * 256 + threadIdx.x;
    int m = t >> 7, c = t & 127;
    float v = fmaxf(h1[((size_t)perm1[m] << 7) + c] * sc[c] + sh[c], 0.f);
    h1pb[t] = f2bf(v * tv1[m]);
}

// ---------------- fused: layer2 BN-apply + tanh-scale + pooled accumulate ----------------
__global__ void __launch_bounds__(256) pool_part_kernel(const float* __restrict__ h2,
                                                        const int* __restrict__ perm2,
                                                        const float* __restrict__ tv2,
                                                        const double* __restrict__ dsum,
                                                        const double* __restrict__ dsq,
                                                        const float* __restrict__ g,
                                                        const float* __restrict__ b,
                                                        float* __restrict__ pooled) {
    __shared__ float sc[256], sh[256];
    {
        int c = threadIdx.x;
        double m = dsum[c] / (double)N1c;
        double var = dsq[c] / (double)N1c - m * m;
        float s = g[c] * (float)(1.0 / sqrt(var + 1e-5));
        sc[c] = s; sh[c] = b[c] - (float)m * s;
    }
    __syncthreads();
    int gg = blockIdx.x, p = blockIdx.y, c = threadIdx.x;
    float s = 0.f;
    for (int j = 0; j < 64; j++) {
        int m = gg * K2c + p * 64 + j;
        int row = perm2[m];
        float v = fmaxf(h2[((size_t)row << 8) + c] * sc[c] + sh[c], 0.f);
        s += v * tv2[m];
    }
    atomicAdd(&pooled[gg * H2c + c], s);
}

__global__ void __launch_bounds__(256) pool_fin_kernel(const float* __restrict__ pooled,
                                                       const float* __restrict__ Wlin,
                                                       const float* __restrict__ blin,
                                                       float* __restrict__ out) {
    __shared__ float p0s[256], p1s[256];
    int g = blockIdx.x, c = threadIdx.x;
    float s = fmaxf(pooled[g * 256 + c] * (1.f / (float)K2c), 0.f);
    p0s[c] = s * Wlin[c * 2 + 0];
    p1s[c] = s * Wlin[c * 2 + 1];
    __syncthreads();
    for (int off = 128; off; off >>= 1) {
        if (c < off) { p0s[c] += p0s[c + off]; p1s[c] += p1s[c + off]; }
        __syncthreads();
    }
    if (c == 0) {
        float o0 = p0s[0] + blin[0], o1 = p1s[0] + blin[1];
        float m = fmaxf(o0, o1);
        float e0 = expf(o0 - m), e1 = expf(o1 - m);
        float inv = 1.f / (e0 + e1);
        out[g * 2 + 0] = e0 * inv;
        out[g * 2 + 1] = e1 * inv;
    }
}

extern "C" void kernel_launch(void* const* d_in, const int* in_sizes, int n_in,
                              void* d_out, int out_size, void* d_ws, size_t ws_size,
                              hipStream_t stream) {
    const float* x      = (const float*)d_in[0];
    const int*   ei     = (const int*)d_in[1];
    const int*   src    = ei;
    const int*   tgt    = ei + Ee;
    const float* W1l    = (const float*)d_in[3];
    const float* b1l    = (const float*)d_in[4];
    const float* W1r    = (const float*)d_in[5];
    const float* bn1g   = (const float*)d_in[6];
    const float* bn1b   = (const float*)d_in[7];
    const float* p1Wrel = (const float*)d_in[8];
    const float* p1brel = (const float*)d_in[9];
    const float* p1Wroot= (const float*)d_in[10];
    const float* W2l    = (const float*)d_in[11];
    const float* b2l    = (const float*)d_in[12];
    const float* W2r    = (const float*)d_in[13];
    const float* bn2g   = (const float*)d_in[14];
    const float* bn2b   = (const float*)d_in[15];
    const float* p2Wrel = (const float*)d_in[16];
    const float* p2brel = (const float*)d_in[17];
    const float* p2Wroot= (const float*)d_in[18];
    const float* Wlin   = (const float*)d_in[19];
    const float* blin   = (const float*)d_in[20];
    float* out = (float*)d_out;
    char* ws = (char*)d_ws;

    size_t o = 0;
    auto A = [&](size_t b) { size_t r = o; o += (b + 255) & ~(size_t)255; return r; };
    size_t oBIG1 = A((size_t)Nn * H1c * 4);        // h1 / h2 f32
    size_t oBIG2 = A((size_t)Nn * INc * 4);        // xb + aggb1 bf16
    size_t oPB   = A((size_t)N1c * H1c * 4);       // h1pb + aggb2 bf16
    size_t oCol1 = A((size_t)Nn * SLAB * 4);
    size_t oCol2 = A((size_t)N1c * SLAB * 4);
    size_t oWc1  = A((size_t)Nn * 4);
    size_t oR1   = A((size_t)Nn * 4);
    size_t oRoot1= A((size_t)Nn * 4);
    size_t oPerm1= A((size_t)N1c * 4);
    size_t oTv1  = A((size_t)N1c * 4);
    size_t oWc2  = A((size_t)N1c * 4);
    size_t oR2   = A((size_t)N1c * 4);
    size_t oRoot2= A((size_t)N1c * 4);
    size_t oPerm2= A((size_t)N2c * 4);
    size_t oTv2  = A((size_t)N2c * 4);
    size_t oDst  = A(768 * 8);
    size_t oWt1l = A(8192 * 2);
    size_t oWt1r = A(8192 * 2);
    size_t oWt2l = A(32768 * 2);
    size_t oWt2r = A(32768 * 2);
    size_t oPool = A(Bg * H2c * 4);
    (void)ws_size; (void)in_sizes; (void)n_in; (void)out_size;

    float* h1    = (float*)(ws + oBIG1);
    float* h2    = (float*)(ws + oBIG1);
    ushort* xb   = (ushort*)(ws + oBIG2);
    ushort* aggb1= (ushort*)(ws + oBIG2 + (size_t)Nn * 64 * 2);
    ushort* h1pb = (ushort*)(ws + oPB);
    ushort* aggb2= (ushort*)(ws + oPB + (size_t)N1c * 128 * 2);
    int* col1    = (int*)(ws + oCol1);
    int* col2    = (int*)(ws + oCol2);
    int* wc1     = (int*)(ws + oWc1);
    float* r1    = (float*)(ws + oR1);
    float* root1 = (float*)(ws + oRoot1);
    int* perm1   = (int*)(ws + oPerm1);
    float* tv1   = (float*)(ws + oTv1);
    int* wc2     = (int*)(ws + oWc2);
    float* r2    = (float*)(ws + oR2);
    float* root2 = (float*)(ws + oRoot2);
    int* perm2   = (int*)(ws + oPerm2);
    float* tv2   = (float*)(ws + oTv2);
    double* dsum1= (double*)(ws + oDst);
    double* dsq1 = dsum1 + 128;
    double* dsum2= dsum1 + 256;
    double* dsq2 = dsum1 + 512;
    ushort* T1l  = (ushort*)(ws + oWt1l);
    ushort* T1r  = (ushort*)(ws + oWt1r);
    ushort* T2l  = (ushort*)(ws + oWt2l);
    ushort* T2r  = (ushort*)(ws + oWt2r);
    float* pooled= (float*)(ws + oPool);

    // 1. prep
    prep_kernel<<<(PREP_TOTAL + 255) / 256, 256, 0, stream>>>(
        x, W1l, W1r, W2l, W2r, T1l, T1r, T2l, T2r, xb, wc1, (int*)dsum1, (int*)pooled);

    // 2. layer1 slab CSR
    fill1_kernel<<<Ee / 256, 256, 0, stream>>>(src, tgt, wc1, col1);

    // 3-4. SAGEConv1 (+ fused BN1 stats)
    agg1_kernel<<<2048, 256, 0, stream>>>(xb, wc1, col1, aggb1);
    {
        dim3 g(Nn / 128, H1c / 64);
        gemm_mfma_kernel<INc, H1c><<<g, 256, 0, stream>>>(aggb1, xb, T1l, T1r, b1l, h1,
                                                          dsum1, dsq1);
    }

    // 5-6. score + topk1 (edge-parallel scores, fused map + layer2 fill)
    score_kernel<H1c><<<Nn / 4, 256, 0, stream>>>(h1, dsum1, dsq1, bn1g, bn1b, p1Wrel,
                                                  p1Wroot, r1, root1, Nn);
    topk1_kernel<<<Bg, 1024, 0, stream>>>(r1, root1, src, tgt, p1brel, perm1, tv1,
                                          wc2, col2);

    // 7. BN-apply gather (h1 -> h1pb)
    gather1_kernel<<<(N1c * H1c) / 256, 256, 0, stream>>>(h1, perm1, tv1, dsum1, dsq1,
                                                          bn1g, bn1b, h1pb);

    // 8-9. SAGEConv2 (+ fused BN2 stats)
    agg2_kernel<<<2048, 256, 0, stream>>>(h1pb, wc2, col2, aggb2);
    {
        dim3 g(N1c / 128, H2c / 64);
        gemm_mfma_kernel<H1c, H2c><<<g, 256, 0, stream>>>(aggb2, h1pb, T2l, T2r, b2l, h2,
                                                          dsum2, dsq2);
    }

    // 10-11. score + topk2
    score_kernel<H2c><<<N1c / 4, 256, 0, stream>>>(h2, dsum2, dsq2, bn2g, bn2b, p2Wrel,
                                                   p2Wroot, r2, root2, N1c);
    topk2_kernel<<<Bg, 1024, 0, stream>>>(r2, root2, wc2, col2, p2brel, perm2, tv2);

    // 12-13. fused BN-apply + tanh-scale + pool, then readout
    {
        dim3 g(Bg, K2c / 64);
        pool_part_kernel<<<g, 256, 0, stream>>>(h2, perm2, tv2, dsum2, dsq2, bn2g, bn2b,
                                                pooled);
    }
    pool_fin_kernel<<<Bg, 256, 0, stream>>>(pooled, Wlin, blin, out);
}

// Round 10
// 285.099 us; speedup vs baseline: 1.0232x; 1.0232x over previous
//
#include <hip/hip_runtime.h>
#include <math.h>

#define Bg   32
#define NPGc 2048
#define Nn   (Bg*NPGc)      // 65536
#define DEGc 8
#define Ee   (Nn*DEGc)      // 524288
#define EPGc (NPGc*DEGc)    // 16384 edges per graph
#define INc  64
#define H1c  128
#define H2c  256
#define K1c  1024
#define K2c  512
#define N1c  (Bg*K1c)       // 32768
#define N2c  (Bg*K2c)       // 16384
#define SLAB 64             // fixed CSR slab per node

typedef __attribute__((ext_vector_type(8))) short short8;
typedef __attribute__((ext_vector_type(4))) float f32x4;

__device__ __forceinline__ ushort f2bf(float f) {
    uint u = __float_as_uint(f);
    uint r = (u + 0x7fffu + ((u >> 16) & 1u)) >> 16;
    return (ushort)r;
}
__device__ __forceinline__ float bf2f(ushort v) { return __uint_as_float((uint)v << 16); }
__device__ __forceinline__ float bfhi(uint v) { return __uint_as_float(v & 0xffff0000u); }
__device__ __forceinline__ float bflo(uint v) { return __uint_as_float(v << 16); }
__device__ __forceinline__ uint fkey(float f) {
    uint u = __float_as_uint(f);
    return u ^ ((uint)((int)u >> 31) | 0x80000000u);
}

// ---------------- prep: wt transpose + x->bf16 + inits ----------------
__global__ void prep_kernel(const float* __restrict__ x,
                            const float* __restrict__ W1l, const float* __restrict__ W1r,
                            const float* __restrict__ W2l, const float* __restrict__ W2r,
                            ushort* __restrict__ T1l, ushort* __restrict__ T1r,
                            ushort* __restrict__ T2l, ushort* __restrict__ T2r,
                            ushort* __restrict__ xb, int* __restrict__ wc1,
                            int* __restrict__ dstats, int* __restrict__ pooled) {
    int id = blockIdx.x * blockDim.x + threadIdx.x;
    if (id < 8192) {
        int c = id / 64, k = id % 64;
        T1l[id] = f2bf(W1l[k * 128 + c]);
        T1r[id] = f2bf(W1r[k * 128 + c]);
        return;
    }
    id -= 8192;
    if (id < 32768) {
        int c = id / 128, k = id % 128;
        T2l[id] = f2bf(W2l[k * 256 + c]);
        T2r[id] = f2bf(W2r[k * 256 + c]);
        return;
    }
    id -= 32768;
    if (id < 16384) { ((int4*)wc1)[id] = (int4){0, 0, 0, 0}; return; }
    id -= 16384;
    if (id < 384)   { ((int4*)dstats)[id] = (int4){0, 0, 0, 0}; return; }
    id -= 384;
    if (id < 2048)  { ((int4*)pooled)[id] = (int4){0, 0, 0, 0}; return; }
    id -= 2048;
    if (id < Nn * 64 / 4) {  // x -> bf16
        float4 v = ((const float4*)x)[id];
        ushort4 o; o.x = f2bf(v.x); o.y = f2bf(v.y); o.z = f2bf(v.z); o.w = f2bf(v.w);
        ((ushort4*)xb)[id] = o;
    }
}
#define PREP_TOTAL (8192 + 32768 + 16384 + 384 + 2048 + Nn*64/4)

// ---------------- self-counting fill into fixed slabs (wc = cursor -> degree) ---------------
__global__ void fill1_kernel(const int* __restrict__ src, const int* __restrict__ tgt,
                             int* __restrict__ wc1, int* __restrict__ col1) {
    int e = blockIdx.x * blockDim.x + threadIdx.x;
    if (e >= Ee) return;
    int t = tgt[e];
    int p = atomicAdd(&wc1[t], 1);
    col1[t * SLAB + p] = src[e];
}

// ---------------- mean aggregation: 16B/lane gathers, bf16, XCD-swizzled ----------------
__device__ __forceinline__ void acc8(float* a, uint4 v) {
    a[0] += bflo(v.x); a[1] += bfhi(v.x);
    a[2] += bflo(v.y); a[3] += bfhi(v.y);
    a[4] += bflo(v.z); a[5] += bfhi(v.z);
    a[6] += bflo(v.w); a[7] += bfhi(v.w);
}
__device__ __forceinline__ uint4 pack8(const float* a, float inv) {
    uint4 o;
    o.x = (uint)f2bf(a[0] * inv) | ((uint)f2bf(a[1] * inv) << 16);
    o.y = (uint)f2bf(a[2] * inv) | ((uint)f2bf(a[3] * inv) << 16);
    o.z = (uint)f2bf(a[4] * inv) | ((uint)f2bf(a[5] * inv) << 16);
    o.w = (uint)f2bf(a[6] * inv) | ((uint)f2bf(a[7] * inv) << 16);
    return o;
}

__global__ void agg1_kernel(const ushort* __restrict__ xb, const int* __restrict__ deg,
                            const int* __restrict__ col, ushort* __restrict__ out) {
    int b = blockIdx.x;
    int w = ((b & 7) << 8) + (b >> 3);
    int gid = w * 256 + threadIdx.x;
    int node = gid >> 3, ln = gid & 7;
    int bg = node * SLAB, dg = deg[node];
    float a[8] = {0.f, 0.f, 0.f, 0.f, 0.f, 0.f, 0.f, 0.f};
    for (int i = bg; i < bg + dg; i++)
        acc8(a, *(const uint4*)&xb[((size_t)col[i] << 6) + ln * 8]);
    int c = dg < 1 ? 1 : dg;
    *(uint4*)&out[((size_t)node << 6) + ln * 8] = pack8(a, 1.f / (float)c);
}

__global__ void agg2_kernel(const ushort* __restrict__ xb, const int* __restrict__ deg,
                            const int* __restrict__ col, ushort* __restrict__ out) {
    int b = blockIdx.x;
    int w = ((b & 7) << 8) + (b >> 3);
    int gid = w * 256 + threadIdx.x;
    int node = gid >> 4, ln = gid & 15;
    int bg = node * SLAB, dg = deg[node];
    float a[8] = {0.f, 0.f, 0.f, 0.f, 0.f, 0.f, 0.f, 0.f};
    for (int i = bg; i < bg + dg; i++)
        acc8(a, *(const uint4*)&xb[((size_t)col[i] << 7) + ln * 8]);
    int c = dg < 1 ? 1 : dg;
    *(uint4*)&out[((size_t)node << 7) + ln * 8] = pack8(a, 1.f / (float)c);
}

// -- MFMA GEMM 128x64 tile; bf16 out; fused per-channel BN stats from f32 acc (exact) --------
template<int K, int COUT>
__global__ __launch_bounds__(256) void gemm_mfma_kernel(
        const ushort* __restrict__ Aagg, const ushort* __restrict__ Ax,
        const ushort* __restrict__ Wtl, const ushort* __restrict__ Wtr,
        const float* __restrict__ bias, ushort* __restrict__ out,
        double* __restrict__ dsum, double* __restrict__ dsq) {
    __shared__ ushort As[2][128][72];
    __shared__ ushort Bs[2][64][72];
    __shared__ float bsumS[2][64], bsqS[2][64];
    int m0 = blockIdx.x * 128;
    int c0 = blockIdx.y * 64;
    int lane = threadIdx.x & 63;
    int wid = threadIdx.x >> 6;
    int wr = (wid & 1) * 64, wc = (wid >> 1) * 32;
    int l16 = lane & 15, quad = lane >> 4;

    f32x4 acc[4][2];
#pragma unroll
    for (int a = 0; a < 4; a++)
#pragma unroll
        for (int b = 0; b < 2; b++) acc[a][b] = (f32x4){0.f, 0.f, 0.f, 0.f};

    for (int kk0 = 0; kk0 < K; kk0 += 64) {
        for (int idx = threadIdx.x; idx < 1024; idx += 256) {
            int r = idx >> 3, ck = (idx & 7) * 8;
            *(uint4*)&As[0][r][ck] = *(const uint4*)&Aagg[(size_t)(m0 + r) * K + kk0 + ck];
            *(uint4*)&As[1][r][ck] = *(const uint4*)&Ax[(size_t)(m0 + r) * K + kk0 + ck];
        }
        for (int idx = threadIdx.x; idx < 512; idx += 256) {
            int r = idx >> 3, ck = (idx & 7) * 8;
            *(uint4*)&Bs[0][r][ck] = *(const uint4*)&Wtl[(size_t)(c0 + r) * K + kk0 + ck];
            *(uint4*)&Bs[1][r][ck] = *(const uint4*)&Wtr[(size_t)(c0 + r) * K + kk0 + ck];
        }
        __syncthreads();
#pragma unroll
        for (int kk = 0; kk < 64; kk += 32) {
            short8 a[2][4], b[2][2];
#pragma unroll
            for (int s = 0; s < 2; s++)
#pragma unroll
                for (int mt = 0; mt < 4; mt++)
                    a[s][mt] = *(const short8*)&As[s][wr + mt * 16 + l16][kk + quad * 8];
#pragma unroll
            for (int s = 0; s < 2; s++)
#pragma unroll
                for (int nt = 0; nt < 2; nt++)
                    b[s][nt] = *(const short8*)&Bs[s][wc + nt * 16 + l16][kk + quad * 8];
#pragma unroll
            for (int mt = 0; mt < 4; mt++)
#pragma unroll
                for (int nt = 0; nt < 2; nt++) {
                    acc[mt][nt] = __builtin_amdgcn_mfma_f32_16x16x32_bf16(
                        a[0][mt], b[0][nt], acc[mt][nt], 0, 0, 0);
                    acc[mt][nt] = __builtin_amdgcn_mfma_f32_16x16x32_bf16(
                        a[1][mt], b[1][nt], acc[mt][nt], 0, 0, 0);
                }
        }
        __syncthreads();
    }
    float s[2] = {0.f, 0.f}, sq[2] = {0.f, 0.f};
#pragma unroll
    for (int nt = 0; nt < 2; nt++) {
        int col = c0 + wc + nt * 16 + l16;
        float bv = bias[col];
#pragma unroll
        for (int mt = 0; mt < 4; mt++)
#pragma unroll
            for (int r = 0; r < 4; r++) {
                int row = m0 + wr + mt * 16 + quad * 4 + r;
                float ov = acc[mt][nt][r] + bv;
                out[(size_t)row * COUT + col] = f2bf(ov);
                s[nt] += ov; sq[nt] += ov * ov;
            }
    }
#pragma unroll
    for (int nt = 0; nt < 2; nt++) {
        float ss = s[nt], qq = sq[nt];
        ss += __shfl_down(ss, 16); qq += __shfl_down(qq, 16);
        ss += __shfl_down(ss, 32); qq += __shfl_down(qq, 32);
        if (quad == 0) {
            bsumS[wid & 1][wc + nt * 16 + l16] = ss;
            bsqS[wid & 1][wc + nt * 16 + l16] = qq;
        }
    }
    __syncthreads();
    if (threadIdx.x < 64) {
        int c = threadIdx.x;
        atomicAdd(&dsum[c0 + c], (double)(bsumS[0][c] + bsumS[1][c]));
        atomicAdd(&dsq[c0 + c], (double)(bsqS[0][c] + bsqS[1][c]));
    }
}

// ---------------- score dots from bf16 h; scale/shift computed in-block ----------------
template<int C>
__global__ __launch_bounds__(256) void score_kernel(const ushort* __restrict__ h,
                                                    const double* __restrict__ dsum,
                                                    const double* __restrict__ dsq,
                                                    const float* __restrict__ g,
                                                    const float* __restrict__ b,
                                                    const float* __restrict__ wrel,
                                                    const float* __restrict__ wroot,
                                                    float* __restrict__ r,
                                                    float* __restrict__ root, int n) {
    __shared__ float sc[C], sh[C], wrl[C], wrt[C];
    if ((int)threadIdx.x < C) {
        int c = threadIdx.x;
        double m = dsum[c] / (double)n;
        double var = dsq[c] / (double)n - m * m;
        float s = g[c] * (float)(1.0 / sqrt(var + 1e-5));
        sc[c] = s; sh[c] = b[c] - (float)m * s;
        wrl[c] = wrel[c]; wrt[c] = wroot[c];
    }
    __syncthreads();
    int gid = blockIdx.x * 256 + threadIdx.x;
    int node = gid >> 6, lane = gid & 63;
    float rr = 0.f, rt = 0.f;
    for (int cp = lane; cp < C / 2; cp += 64) {
        uint v = *(const uint*)&h[(size_t)node * C + 2 * cp];
        int c0 = 2 * cp, c1 = 2 * cp + 1;
        float v0 = fmaxf(bflo(v) * sc[c0] + sh[c0], 0.f);
        float v1 = fmaxf(bfhi(v) * sc[c1] + sh[c1], 0.f);
        rr += v0 * wrl[c0] + v1 * wrl[c1];
        rt += v0 * wrt[c0] + v1 * wrt[c1];
    }
    for (int off = 32; off; off >>= 1) {
        rr += __shfl_down(rr, off);
        rt += __shfl_down(rt, off);
    }
    if (lane == 0) { r[node] = rr; root[node] = rt; }
}

// ------ topk1: edge-parallel score sum + radix select + LDS map + fused layer2 slab fill ----
__global__ void __launch_bounds__(1024) topk1_kernel(const float* __restrict__ r,
                                                     const float* __restrict__ root,
                                                     const int* __restrict__ src,
                                                     const int* __restrict__ tgt,
                                                     const float* __restrict__ brel,
                                                     int* __restrict__ perm,
                                                     float* __restrict__ tval,
                                                     int* __restrict__ wc2,
                                                     int* __restrict__ col2) {
    __shared__ float svals[2048];
    __shared__ int mapL[2048];
    __shared__ int wcL[1024];
    __shared__ uint hist[257];
    __shared__ uint wsum[16];
    __shared__ uint s_b, s_rem;
    int g = blockIdx.x;
    int tid = threadIdx.x;
    int lane = tid & 63, wid = tid >> 6;
    int base = g * NPGc;
    float bv = brel[0];
    svals[tid] = bv + root[base + tid];
    svals[tid + 1024] = bv + root[base + tid + 1024];
    mapL[tid] = -1; mapL[tid + 1024] = -1;
    wcL[tid] = 0;
    if (tid == 256) hist[256] = 0;
    if (tid < 256) hist[tid] = 0;
    __syncthreads();
    for (int j = 0; j < EPGc / 1024; j++) {
        int e = g * EPGc + tid + (j << 10);
        atomicAdd(&svals[tgt[e] - base], r[src[e]]);
    }
    __syncthreads();
    uint prefix = 0, himask = 0, rem = (uint)K1c;
    for (int shift = 24; shift >= 0; shift -= 8) {
        for (int i = tid; i < NPGc; i += 1024) {
            uint kk = fkey(svals[i]);
            if ((kk & himask) == prefix) atomicAdd(&hist[(kk >> shift) & 255], 1);
        }
        __syncthreads();
        if (tid < 64) {
            int L = tid;
            uint h0 = hist[4 * L], h1 = hist[4 * L + 1], h2 = hist[4 * L + 2],
                 h3 = hist[4 * L + 3];
            uint s3 = h3, s2 = h2 + s3, s1 = h1 + s2, s0 = h0 + s1;
            uint v = s0;
            for (int off = 1; off < 64; off <<= 1) {
                uint u = __shfl_down(v, off);
                if (L + off < 64) v += u;
            }
            uint above = v - s0;
            hist[4 * L] = s0 + above;
            hist[4 * L + 1] = s1 + above;
            hist[4 * L + 2] = s2 + above;
            hist[4 * L + 3] = s3 + above;
        }
        __syncthreads();
        if (tid < 256) {
            uint sb = hist[tid], sb1 = hist[tid + 1];
            if (sb >= rem && sb1 < rem) { s_b = (uint)tid; s_rem = rem - sb1; }
        }
        __syncthreads();
        prefix |= (s_b << shift);
        rem = s_rem;
        himask |= (0xFFu << shift);
        if (tid < 256) hist[tid] = 0;
        __syncthreads();
    }
    uint thr = prefix;
    uint m = rem;
    uint gcnt = 0, ecnt = 0, gflags = 0, eflags = 0;
    for (int j = 0; j < 2; j++) {
        uint kk = fkey(svals[tid + (j << 10)]);
        if (kk > thr) { gflags |= 1u << j; gcnt++; }
        else if (kk == thr) { eflags |= 1u << j; ecnt++; }
    }
    uint key = (gcnt << 16) | ecnt;
    uint v = key;
    for (int off = 1; off < 64; off <<= 1) {
        uint u = __shfl_up(v, off);
        if (lane >= off) v += u;
    }
    if (lane == 63) wsum[wid] = v;
    __syncthreads();
    if (tid < 16) {
        uint w0 = wsum[tid], w = w0;
        for (int off = 1; off < 16; off <<= 1) {
            uint u = __shfl_up(w, off);
            if ((int)tid >= off) w += u;
        }
        wsum[tid] = w - w0;
    }
    __syncthreads();
    uint excl = (v - key) + wsum[wid];
    uint gbase = excl >> 16, ebase = excl & 0xFFFFu;
    for (int j = 0; j < 2; j++) {
        bool gt = (gflags >> j) & 1u;
        bool eq = (eflags >> j) & 1u;
        if (gt || (eq && ebase < m)) {
            uint pos = gbase + min(ebase, m);
            int i = tid + (j << 10);
            int o = g * K1c + (int)pos;
            perm[o] = base + i;
            tval[o] = tanhf(svals[i]);
            mapL[i] = o;
        }
        gbase += gt ? 1u : 0u;
        ebase += eq ? 1u : 0u;
    }
    __syncthreads();
    int nbase = g * K1c;
    for (int j = 0; j < EPGc / 1024; j++) {
        int e = g * EPGc + tid + (j << 10);
        int ns = mapL[src[e] - base];
        int nt = mapL[tgt[e] - base];
        if (ns >= 0 && nt >= 0) {
            int p = atomicAdd(&wcL[nt - nbase], 1);
            col2[nt * SLAB + p] = ns;
        }
    }
    __syncthreads();
    wc2[nbase + tid] = wcL[tid];
}

// ---------------- topk2: serial slab score + radix select ----------------
__global__ void __launch_bounds__(1024) topk2_kernel(const float* __restrict__ r,
                                                     const float* __restrict__ root,
                                                     const int* __restrict__ deg,
                                                     const int* __restrict__ col,
                                                     const float* __restrict__ brel,
                                                     int* __restrict__ perm,
                                                     float* __restrict__ tval) {
    __shared__ float svals[1024];
    __shared__ uint hist[257];
    __shared__ uint wsum[16];
    __shared__ uint s_b, s_rem;
    int g = blockIdx.x;
    int tid = threadIdx.x;
    int lane = tid & 63, wid = tid >> 6;
    float bv = brel[0];
    {
        int gi = g * K1c + tid;
        float acc = bv + root[gi];
        int e0 = gi * SLAB, e1 = e0 + deg[gi];
        for (int e = e0; e < e1; e++) acc += r[col[e]];
        svals[tid] = acc;
    }
    if (tid == 256) hist[256] = 0;
    if (tid < 256) hist[tid] = 0;
    __syncthreads();

    uint prefix = 0, himask = 0, rem = (uint)K2c;
    for (int shift = 24; shift >= 0; shift -= 8) {
        {
            uint kk = fkey(svals[tid]);
            if ((kk & himask) == prefix) atomicAdd(&hist[(kk >> shift) & 255], 1);
        }
        __syncthreads();
        if (tid < 64) {
            int L = tid;
            uint h0 = hist[4 * L], h1 = hist[4 * L + 1], h2 = hist[4 * L + 2],
                 h3 = hist[4 * L + 3];
            uint s3 = h3, s2 = h2 + s3, s1 = h1 + s2, s0 = h0 + s1;
            uint v = s0;
            for (int off = 1; off < 64; off <<= 1) {
                uint u = __shfl_down(v, off);
                if (L + off < 64) v += u;
            }
            uint above = v - s0;
            hist[4 * L] = s0 + above;
            hist[4 * L + 1] = s1 + above;
            hist[4 * L + 2] = s2 + above;
            hist[4 * L + 3] = s3 + above;
        }
        __syncthreads();
        if (tid < 256) {
            uint sb = hist[tid], sb1 = hist[tid + 1];
            if (sb >= rem && sb1 < rem) { s_b = (uint)tid; s_rem = rem - sb1; }
        }
        __syncthreads();
        prefix |= (s_b << shift);
        rem = s_rem;
        himask |= (0xFFu << shift);
        if (tid < 256) hist[tid] = 0;
        __syncthreads();
    }
    uint thr = prefix;
    uint m = rem;

    uint kk = fkey(svals[tid]);
    bool gt = kk > thr, eq = kk == thr;
    uint key = (gt ? 0x10000u : 0u) | (eq ? 1u : 0u);
    uint v = key;
    for (int off = 1; off < 64; off <<= 1) {
        uint u = __shfl_up(v, off);
        if (lane >= off) v += u;
    }
    if (lane == 63) wsum[wid] = v;
    __syncthreads();
    if (tid < 16) {
        uint w0 = wsum[tid], w = w0;
        for (int off = 1; off < 16; off <<= 1) {
            uint u = __shfl_up(w, off);
            if ((int)tid >= off) w += u;
        }
        wsum[tid] = w - w0;
    }
    __syncthreads();
    uint excl = (v - key) + wsum[wid];
    uint gbase = excl >> 16, ebase = excl & 0xFFFFu;
    if (gt || (eq && ebase < m)) {
        uint pos = gbase + min(ebase, m);
        int o = g * K2c + (int)pos;
        perm[o] = g * K1c + tid;
        tval[o] = tanhf(svals[tid]);
    }
}

// -------- gather1: BN-apply + tanh-scale gather bf16 h1 -> h1pb (bf16) --------
__global__ void __launch_bounds__(256) gather1_kernel(
        const ushort* __restrict__ h1, const int* __restrict__ perm1,
        const float* __restrict__ tv1, const double* __restrict__ dsum,
        const double* __restrict__ dsq, const float* __restrict__ g,
        const float* __restrict__ b, ushort* __restrict__ h1pb) {
    __shared__ float sc[128], sh[128];
    if (threadIdx.x < 128) {
        int c = threadIdx.x;
        double m = dsum[c] / (double)Nn;
        double var = dsq[c] / (double)Nn - m * m;
        float s = g[c] * (float)(1.0 / sqrt(var + 1e-5));
        sc[c] = s; sh[c] = b[c] - (float)m * s;
    }
    __syncthreads();
    int t = blockIdx.x * 256 + threadIdx.x;
    int m = t >> 7, c = t & 127;
    float v = fmaxf(bf2f(h1[((size_t)perm1[m] << 7) + c]) * sc[c] + sh[c], 0.f);
    h1pb[t] = f2bf(v * tv1[m]);
}

// ---------------- fused: layer2 BN-apply + tanh-scale + pooled accumulate ----------------
__global__ void __launch_bounds__(256) pool_part_kernel(const ushort* __restrict__ h2,
                                                        const int* __restrict__ perm2,
                                                        const float* __restrict__ tv2,
                                                        const double* __restrict__ dsum,
                                                        const double* __restrict__ dsq,
                                                        const float* __restrict__ g,
                                                        const float* __restrict__ b,
                                                        float* __restrict__ pooled) {
    __shared__ float sc[256], sh[256];
    {
        int c = threadIdx.x;
        double m = dsum[c] / (double)N1c;
        double var = dsq[c] / (double)N1c - m * m;
        float s = g[c] * (float)(1.0 / sqrt(var + 1e-5));
        sc[c] = s; sh[c] = b[c] - (float)m * s;
    }
    __syncthreads();
    int gg = blockIdx.x, p = blockIdx.y, c = threadIdx.x;
    float s = 0.f;
    for (int j = 0; j < 64; j++) {
        int m = gg * K2c + p * 64 + j;
        int row = perm2[m];
        float v = fmaxf(bf2f(h2[((size_t)row << 8) + c]) * sc[c] + sh[c], 0.f);
        s += v * tv2[m];
    }
    atomicAdd(&pooled[gg * H2c + c], s);
}

__global__ void __launch_bounds__(256) pool_fin_kernel(const float* __restrict__ pooled,
                                                       const float* __restrict__ Wlin,
                                                       const float* __restrict__ blin,
                                                       float* __restrict__ out) {
    __shared__ float p0s[256], p1s[256];
    int g = blockIdx.x, c = threadIdx.x;
    float s = fmaxf(pooled[g * 256 + c] * (1.f / (float)K2c), 0.f);
    p0s[c] = s * Wlin[c * 2 + 0];
    p1s[c] = s * Wlin[c * 2 + 1];
    __syncthreads();
    for (int off = 128; off; off >>= 1) {
        if (c < off) { p0s[c] += p0s[c + off]; p1s[c] += p1s[c + off]; }
        __syncthreads();
    }
    if (c == 0) {
        float o0 = p0s[0] + blin[0], o1 = p1s[0] + blin[1];
        float m = fmaxf(o0, o1);
        float e0 = expf(o0 - m), e1 = expf(o1 - m);
        float inv = 1.f / (e0 + e1);
        out[g * 2 + 0] = e0 * inv;
        out[g * 2 + 1] = e1 * inv;
    }
}

extern "C" void kernel_launch(void* const* d_in, const int* in_sizes, int n_in,
                              void* d_out, int out_size, void* d_ws, size_t ws_size,
                              hipStream_t stream) {
    const float* x      = (const float*)d_in[0];
    const int*   ei     = (const int*)d_in[1];
    const int*   src    = ei;
    const int*   tgt    = ei + Ee;
    const float* W1l    = (const float*)d_in[3];
    const float* b1l    = (const float*)d_in[4];
    const float* W1r    = (const float*)d_in[5];
    const float* bn1g   = (const float*)d_in[6];
    const float* bn1b   = (const float*)d_in[7];
    const float* p1Wrel = (const float*)d_in[8];
    const float* p1brel = (const float*)d_in[9];
    const float* p1Wroot= (const float*)d_in[10];
    const float* W2l    = (const float*)d_in[11];
    const float* b2l    = (const float*)d_in[12];
    const float* W2r    = (const float*)d_in[13];
    const float* bn2g   = (const float*)d_in[14];
    const float* bn2b   = (const float*)d_in[15];
    const float* p2Wrel = (const float*)d_in[16];
    const float* p2brel = (const float*)d_in[17];
    const float* p2Wroot= (const float*)d_in[18];
    const float* Wlin   = (const float*)d_in[19];
    const float* blin   = (const float*)d_in[20];
    float* out = (float*)d_out;
    char* ws = (char*)d_ws;

    size_t o = 0;
    auto A = [&](size_t b) { size_t r = o; o += (b + 255) & ~(size_t)255; return r; };
    size_t oBIG1 = A((size_t)Nn * H1c * 2);        // h1 / h2 bf16 (16.8 MB)
    size_t oBIG2 = A((size_t)Nn * INc * 4);        // xb + aggb1 bf16
    size_t oPB   = A((size_t)N1c * H1c * 4);       // h1pb + aggb2 bf16
    size_t oCol1 = A((size_t)Nn * SLAB * 4);
    size_t oCol2 = A((size_t)N1c * SLAB * 4);
    size_t oWc1  = A((size_t)Nn * 4);
    size_t oR1   = A((size_t)Nn * 4);
    size_t oRoot1= A((size_t)Nn * 4);
    size_t oPerm1= A((size_t)N1c * 4);
    size_t oTv1  = A((size_t)N1c * 4);
    size_t oWc2  = A((size_t)N1c * 4);
    size_t oR2   = A((size_t)N1c * 4);
    size_t oRoot2= A((size_t)N1c * 4);
    size_t oPerm2= A((size_t)N2c * 4);
    size_t oTv2  = A((size_t)N2c * 4);
    size_t oDst  = A(768 * 8);
    size_t oWt1l = A(8192 * 2);
    size_t oWt1r = A(8192 * 2);
    size_t oWt2l = A(32768 * 2);
    size_t oWt2r = A(32768 * 2);
    size_t oPool = A(Bg * H2c * 4);
    (void)ws_size; (void)in_sizes; (void)n_in; (void)out_size;

    ushort* h1   = (ushort*)(ws + oBIG1);
    ushort* h2   = (ushort*)(ws + oBIG1);
    ushort* xb   = (ushort*)(ws + oBIG2);
    ushort* aggb1= (ushort*)(ws + oBIG2 + (size_t)Nn * 64 * 2);
    ushort* h1pb = (ushort*)(ws + oPB);
    ushort* aggb2= (ushort*)(ws + oPB + (size_t)N1c * 128 * 2);
    int* col1    = (int*)(ws + oCol1);
    int* col2    = (int*)(ws + oCol2);
    int* wc1     = (int*)(ws + oWc1);
    float* r1    = (float*)(ws + oR1);
    float* root1 = (float*)(ws + oRoot1);
    int* perm1   = (int*)(ws + oPerm1);
    float* tv1   = (float*)(ws + oTv1);
    int* wc2     = (int*)(ws + oWc2);
    float* r2    = (float*)(ws + oR2);
    float* root2 = (float*)(ws + oRoot2);
    int* perm2   = (int*)(ws + oPerm2);
    float* tv2   = (float*)(ws + oTv2);
    double* dsum1= (double*)(ws + oDst);
    double* dsq1 = dsum1 + 128;
    double* dsum2= dsum1 + 256;
    double* dsq2 = dsum1 + 512;
    ushort* T1l  = (ushort*)(ws + oWt1l);
    ushort* T1r  = (ushort*)(ws + oWt1r);
    ushort* T2l  = (ushort*)(ws + oWt2l);
    ushort* T2r  = (ushort*)(ws + oWt2r);
    float* pooled= (float*)(ws + oPool);

    // 1. prep
    prep_kernel<<<(PREP_TOTAL + 255) / 256, 256, 0, stream>>>(
        x, W1l, W1r, W2l, W2r, T1l, T1r, T2l, T2r, xb, wc1, (int*)dsum1, (int*)pooled);

    // 2. layer1 slab CSR
    fill1_kernel<<<Ee / 256, 256, 0, stream>>>(src, tgt, wc1, col1);

    // 3-4. SAGEConv1 (+ fused BN1 stats)
    agg1_kernel<<<2048, 256, 0, stream>>>(xb, wc1, col1, aggb1);
    {
        dim3 g(Nn / 128, H1c / 64);
        gemm_mfma_kernel<INc, H1c><<<g, 256, 0, stream>>>(aggb1, xb, T1l, T1r, b1l, h1,
                                                          dsum1, dsq1);
    }

    // 5-6. score + topk1 (edge-parallel scores, fused map + layer2 fill)
    score_kernel<H1c><<<Nn / 4, 256, 0, stream>>>(h1, dsum1, dsq1, bn1g, bn1b, p1Wrel,
                                                  p1Wroot, r1, root1, Nn);
    topk1_kernel<<<Bg, 1024, 0, stream>>>(r1, root1, src, tgt, p1brel, perm1, tv1,
                                          wc2, col2);

    // 7. BN-apply gather (h1 -> h1pb)
    gather1_kernel<<<(N1c * H1c) / 256, 256, 0, stream>>>(h1, perm1, tv1, dsum1, dsq1,
                                                          bn1g, bn1b, h1pb);

    // 8-9. SAGEConv2 (+ fused BN2 stats)
    agg2_kernel<<<2048, 256, 0, stream>>>(h1pb, wc2, col2, aggb2);
    {
        dim3 g(N1c / 128, H2c / 64);
        gemm_mfma_kernel<H1c, H2c><<<g, 256, 0, stream>>>(aggb2, h1pb, T2l, T2r, b2l, h2,
                                                          dsum2, dsq2);
    }

    // 10-11. score + topk2
    score_kernel<H2c><<<N1c / 4, 256, 0, stream>>>(h2, dsum2, dsq2, bn2g, bn2b, p2Wrel,
                                                   p2Wroot, r2, root2, N1c);
    topk2_kernel<<<Bg, 1024, 0, stream>>>(r2, root2, wc2, col2, p2brel, perm2, tv2);

    // 12-13. fused BN-apply + tanh-scale + pool, then readout
    {
        dim3 g(Bg, K2c / 64);
        pool_part_kernel<<<g, 256, 0, stream>>>(h2, perm2, tv2, dsum2, dsq2, bn2g, bn2b,
                                                pooled);
    }
    pool_fin_kernel<<<Bg, 256, 0, stream>>>(pooled, Wlin, blin, out);
}

// Round 11
// 282.461 us; speedup vs baseline: 1.0328x; 1.0093x over previous
//
#include <hip/hip_runtime.h>
#include <math.h>

#define Bg   32
#define NPGc 2048
#define Nn   (Bg*NPGc)      // 65536
#define DEGc 8
#define Ee   (Nn*DEGc)      // 524288
#define EPGc (NPGc*DEGc)    // 16384 edges per graph
#define INc  64
#define H1c  128
#define H2c  256
#define K1c  1024
#define K2c  512
#define N1c  (Bg*K1c)       // 32768
#define N2c  (Bg*K2c)       // 16384
#define SLAB 64             // fixed CSR slab per node

typedef __attribute__((ext_vector_type(8))) short short8;
typedef __attribute__((ext_vector_type(4))) float f32x4;

__device__ __forceinline__ ushort f2bf(float f) {
    uint u = __float_as_uint(f);
    uint r = (u + 0x7fffu + ((u >> 16) & 1u)) >> 16;
    return (ushort)r;
}
__device__ __forceinline__ float bf2f(ushort v) { return __uint_as_float((uint)v << 16); }
__device__ __forceinline__ float bfhi(uint v) { return __uint_as_float(v & 0xffff0000u); }
__device__ __forceinline__ float bflo(uint v) { return __uint_as_float(v << 16); }
__device__ __forceinline__ uint fkey(float f) {
    uint u = __float_as_uint(f);
    return u ^ ((uint)((int)u >> 31) | 0x80000000u);
}

// ---------------- prep: wt transpose + x->bf16 + inits ----------------
__global__ void prep_kernel(const float* __restrict__ x,
                            const float* __restrict__ W1l, const float* __restrict__ W1r,
                            const float* __restrict__ W2l, const float* __restrict__ W2r,
                            ushort* __restrict__ T1l, ushort* __restrict__ T1r,
                            ushort* __restrict__ T2l, ushort* __restrict__ T2r,
                            ushort* __restrict__ xb, int* __restrict__ wc1,
                            int* __restrict__ dstats, int* __restrict__ pooled) {
    int id = blockIdx.x * blockDim.x + threadIdx.x;
    if (id < 8192) {
        int c = id / 64, k = id % 64;
        T1l[id] = f2bf(W1l[k * 128 + c]);
        T1r[id] = f2bf(W1r[k * 128 + c]);
        return;
    }
    id -= 8192;
    if (id < 32768) {
        int c = id / 128, k = id % 128;
        T2l[id] = f2bf(W2l[k * 256 + c]);
        T2r[id] = f2bf(W2r[k * 256 + c]);
        return;
    }
    id -= 32768;
    if (id < 16384) { ((int4*)wc1)[id] = (int4){0, 0, 0, 0}; return; }
    id -= 16384;
    if (id < 384)   { ((int4*)dstats)[id] = (int4){0, 0, 0, 0}; return; }
    id -= 384;
    if (id < 2048)  { ((int4*)pooled)[id] = (int4){0, 0, 0, 0}; return; }
    id -= 2048;
    if (id < Nn * 64 / 4) {  // x -> bf16
        float4 v = ((const float4*)x)[id];
        ushort4 o; o.x = f2bf(v.x); o.y = f2bf(v.y); o.z = f2bf(v.z); o.w = f2bf(v.w);
        ((ushort4*)xb)[id] = o;
    }
}
#define PREP_TOTAL (8192 + 32768 + 16384 + 384 + 2048 + Nn*64/4)

// ---------------- self-counting fill into fixed slabs (wc = cursor -> degree) ---------------
__global__ void fill1_kernel(const int* __restrict__ src, const int* __restrict__ tgt,
                             int* __restrict__ wc1, int* __restrict__ col1) {
    int e = blockIdx.x * blockDim.x + threadIdx.x;
    if (e >= Ee) return;
    int t = tgt[e];
    int p = atomicAdd(&wc1[t], 1);
    col1[t * SLAB + p] = src[e];
}

// ---------------- mean aggregation: ILP gathers (preloaded indices), bf16 ----------------
__device__ __forceinline__ void acc8(float* a, uint4 v) {
    a[0] += bflo(v.x); a[1] += bfhi(v.x);
    a[2] += bflo(v.y); a[3] += bfhi(v.y);
    a[4] += bflo(v.z); a[5] += bfhi(v.z);
    a[6] += bflo(v.w); a[7] += bfhi(v.w);
}
__device__ __forceinline__ uint4 pack8(const float* a, float inv) {
    uint4 o;
    o.x = (uint)f2bf(a[0] * inv) | ((uint)f2bf(a[1] * inv) << 16);
    o.y = (uint)f2bf(a[2] * inv) | ((uint)f2bf(a[3] * inv) << 16);
    o.z = (uint)f2bf(a[4] * inv) | ((uint)f2bf(a[5] * inv) << 16);
    o.w = (uint)f2bf(a[6] * inv) | ((uint)f2bf(a[7] * inv) << 16);
    return o;
}

// layer1: C=64, 8 lanes/node x 8ch; indices preloaded -> 8 independent gathers.
__global__ void agg1_kernel(const ushort* __restrict__ xb, const int* __restrict__ deg,
                            const int* __restrict__ col, ushort* __restrict__ out) {
    int b = blockIdx.x;
    int w = ((b & 7) << 8) + (b >> 3);
    int gid = w * 256 + threadIdx.x;
    int node = gid >> 3, ln = gid & 7;
    int bg = node * SLAB, dg = deg[node];
    int4 c0 = *(const int4*)&col[bg];       // slab 256B-aligned; poison entries read-only
    int4 c1 = *(const int4*)&col[bg + 4];
    int idx[8] = {c0.x, c0.y, c0.z, c0.w, c1.x, c1.y, c1.z, c1.w};
    float a[8] = {0.f, 0.f, 0.f, 0.f, 0.f, 0.f, 0.f, 0.f};
#pragma unroll
    for (int j = 0; j < 8; j++)
        if (j < dg) acc8(a, *(const uint4*)&xb[((size_t)idx[j] << 6) + ln * 8]);
    for (int i = bg + 8; i < bg + dg; i++)   // tail deg>8
        acc8(a, *(const uint4*)&xb[((size_t)col[i] << 6) + ln * 8]);
    int c = dg < 1 ? 1 : dg;
    *(uint4*)&out[((size_t)node << 6) + ln * 8] = pack8(a, 1.f / (float)c);
}

// layer2: C=128, 16 lanes/node x 8ch.
__global__ void agg2_kernel(const ushort* __restrict__ xb, const int* __restrict__ deg,
                            const int* __restrict__ col, ushort* __restrict__ out) {
    int b = blockIdx.x;
    int w = ((b & 7) << 8) + (b >> 3);
    int gid = w * 256 + threadIdx.x;
    int node = gid >> 4, ln = gid & 15;
    int bg = node * SLAB, dg = deg[node];
    int4 c0 = *(const int4*)&col[bg];
    int4 c1 = *(const int4*)&col[bg + 4];
    int idx[8] = {c0.x, c0.y, c0.z, c0.w, c1.x, c1.y, c1.z, c1.w};
    float a[8] = {0.f, 0.f, 0.f, 0.f, 0.f, 0.f, 0.f, 0.f};
#pragma unroll
    for (int j = 0; j < 8; j++)
        if (j < dg) acc8(a, *(const uint4*)&xb[((size_t)idx[j] << 7) + ln * 8]);
    for (int i = bg + 8; i < bg + dg; i++)
        acc8(a, *(const uint4*)&xb[((size_t)col[i] << 7) + ln * 8]);
    int c = dg < 1 ? 1 : dg;
    *(uint4*)&out[((size_t)node << 7) + ln * 8] = pack8(a, 1.f / (float)c);
}

// -- MFMA GEMM 128x64 tile; bf16 out; fused per-channel BN stats from f32 acc (exact) --------
template<int K, int COUT>
__global__ __launch_bounds__(256) void gemm_mfma_kernel(
        const ushort* __restrict__ Aagg, const ushort* __restrict__ Ax,
        const ushort* __restrict__ Wtl, const ushort* __restrict__ Wtr,
        const float* __restrict__ bias, ushort* __restrict__ out,
        double* __restrict__ dsum, double* __restrict__ dsq) {
    __shared__ ushort As[2][128][72];
    __shared__ ushort Bs[2][64][72];
    __shared__ float bsumS[2][64], bsqS[2][64];
    int m0 = blockIdx.x * 128;
    int c0 = blockIdx.y * 64;
    int lane = threadIdx.x & 63;
    int wid = threadIdx.x >> 6;
    int wr = (wid & 1) * 64, wc = (wid >> 1) * 32;
    int l16 = lane & 15, quad = lane >> 4;

    f32x4 acc[4][2];
#pragma unroll
    for (int a = 0; a < 4; a++)
#pragma unroll
        for (int b = 0; b < 2; b++) acc[a][b] = (f32x4){0.f, 0.f, 0.f, 0.f};

    for (int kk0 = 0; kk0 < K; kk0 += 64) {
        for (int idx = threadIdx.x; idx < 1024; idx += 256) {
            int r = idx >> 3, ck = (idx & 7) * 8;
            *(uint4*)&As[0][r][ck] = *(const uint4*)&Aagg[(size_t)(m0 + r) * K + kk0 + ck];
            *(uint4*)&As[1][r][ck] = *(const uint4*)&Ax[(size_t)(m0 + r) * K + kk0 + ck];
        }
        for (int idx = threadIdx.x; idx < 512; idx += 256) {
            int r = idx >> 3, ck = (idx & 7) * 8;
            *(uint4*)&Bs[0][r][ck] = *(const uint4*)&Wtl[(size_t)(c0 + r) * K + kk0 + ck];
            *(uint4*)&Bs[1][r][ck] = *(const uint4*)&Wtr[(size_t)(c0 + r) * K + kk0 + ck];
        }
        __syncthreads();
#pragma unroll
        for (int kk = 0; kk < 64; kk += 32) {
            short8 a[2][4], b[2][2];
#pragma unroll
            for (int s = 0; s < 2; s++)
#pragma unroll
                for (int mt = 0; mt < 4; mt++)
                    a[s][mt] = *(const short8*)&As[s][wr + mt * 16 + l16][kk + quad * 8];
#pragma unroll
            for (int s = 0; s < 2; s++)
#pragma unroll
                for (int nt = 0; nt < 2; nt++)
                    b[s][nt] = *(const short8*)&Bs[s][wc + nt * 16 + l16][kk + quad * 8];
#pragma unroll
            for (int mt = 0; mt < 4; mt++)
#pragma unroll
                for (int nt = 0; nt < 2; nt++) {
                    acc[mt][nt] = __builtin_amdgcn_mfma_f32_16x16x32_bf16(
                        a[0][mt], b[0][nt], acc[mt][nt], 0, 0, 0);
                    acc[mt][nt] = __builtin_amdgcn_mfma_f32_16x16x32_bf16(
                        a[1][mt], b[1][nt], acc[mt][nt], 0, 0, 0);
                }
        }
        __syncthreads();
    }
    float s[2] = {0.f, 0.f}, sq[2] = {0.f, 0.f};
#pragma unroll
    for (int nt = 0; nt < 2; nt++) {
        int col = c0 + wc + nt * 16 + l16;
        float bv = bias[col];
#pragma unroll
        for (int mt = 0; mt < 4; mt++)
#pragma unroll
            for (int r = 0; r < 4; r++) {
                int row = m0 + wr + mt * 16 + quad * 4 + r;
                float ov = acc[mt][nt][r] + bv;
                out[(size_t)row * COUT + col] = f2bf(ov);
                s[nt] += ov; sq[nt] += ov * ov;
            }
    }
#pragma unroll
    for (int nt = 0; nt < 2; nt++) {
        float ss = s[nt], qq = sq[nt];
        ss += __shfl_down(ss, 16); qq += __shfl_down(qq, 16);
        ss += __shfl_down(ss, 32); qq += __shfl_down(qq, 32);
        if (quad == 0) {
            bsumS[wid & 1][wc + nt * 16 + l16] = ss;
            bsqS[wid & 1][wc + nt * 16 + l16] = qq;
        }
    }
    __syncthreads();
    if (threadIdx.x < 64) {
        int c = threadIdx.x;
        atomicAdd(&dsum[c0 + c], (double)(bsumS[0][c] + bsumS[1][c]));
        atomicAdd(&dsq[c0 + c], (double)(bsqS[0][c] + bsqS[1][c]));
    }
}

// ---------------- score dots from bf16 h; scale/shift computed in-block ----------------
template<int C>
__global__ __launch_bounds__(256) void score_kernel(const ushort* __restrict__ h,
                                                    const double* __restrict__ dsum,
                                                    const double* __restrict__ dsq,
                                                    const float* __restrict__ g,
                                                    const float* __restrict__ b,
                                                    const float* __restrict__ wrel,
                                                    const float* __restrict__ wroot,
                                                    float* __restrict__ r,
                                                    float* __restrict__ root, int n) {
    __shared__ float sc[C], sh[C], wrl[C], wrt[C];
    if ((int)threadIdx.x < C) {
        int c = threadIdx.x;
        double m = dsum[c] / (double)n;
        double var = dsq[c] / (double)n - m * m;
        float s = g[c] * (float)(1.0 / sqrt(var + 1e-5));
        sc[c] = s; sh[c] = b[c] - (float)m * s;
        wrl[c] = wrel[c]; wrt[c] = wroot[c];
    }
    __syncthreads();
    int gid = blockIdx.x * 256 + threadIdx.x;
    int node = gid >> 6, lane = gid & 63;
    float rr = 0.f, rt = 0.f;
    for (int cp = lane; cp < C / 2; cp += 64) {
        uint v = *(const uint*)&h[(size_t)node * C + 2 * cp];
        int c0 = 2 * cp, c1 = 2 * cp + 1;
        float v0 = fmaxf(bflo(v) * sc[c0] + sh[c0], 0.f);
        float v1 = fmaxf(bfhi(v) * sc[c1] + sh[c1], 0.f);
        rr += v0 * wrl[c0] + v1 * wrl[c1];
        rt += v0 * wrt[c0] + v1 * wrt[c1];
    }
    for (int off = 32; off; off >>= 1) {
        rr += __shfl_down(rr, off);
        rt += __shfl_down(rt, off);
    }
    if (lane == 0) { r[node] = rr; root[node] = rt; }
}

// ------ topk1: edge-parallel score sum + radix select + LDS map + fused layer2 slab fill ----
__global__ void __launch_bounds__(1024) topk1_kernel(const float* __restrict__ r,
                                                     const float* __restrict__ root,
                                                     const int* __restrict__ src,
                                                     const int* __restrict__ tgt,
                                                     const float* __restrict__ brel,
                                                     int* __restrict__ perm,
                                                     float* __restrict__ tval,
                                                     int* __restrict__ wc2,
                                                     int* __restrict__ col2) {
    __shared__ float svals[2048];
    __shared__ int mapL[2048];
    __shared__ int wcL[1024];
    __shared__ uint hist[257];
    __shared__ uint wsum[16];
    __shared__ uint s_b, s_rem;
    int g = blockIdx.x;
    int tid = threadIdx.x;
    int lane = tid & 63, wid = tid >> 6;
    int base = g * NPGc;
    float bv = brel[0];
    svals[tid] = bv + root[base + tid];
    svals[tid + 1024] = bv + root[base + tid + 1024];
    mapL[tid] = -1; mapL[tid + 1024] = -1;
    wcL[tid] = 0;
    if (tid == 256) hist[256] = 0;
    if (tid < 256) hist[tid] = 0;
    __syncthreads();
    for (int j = 0; j < EPGc / 1024; j++) {
        int e = g * EPGc + tid + (j << 10);
        atomicAdd(&svals[tgt[e] - base], r[src[e]]);
    }
    __syncthreads();
    uint prefix = 0, himask = 0, rem = (uint)K1c;
    for (int shift = 24; shift >= 0; shift -= 8) {
        for (int i = tid; i < NPGc; i += 1024) {
            uint kk = fkey(svals[i]);
            if ((kk & himask) == prefix) atomicAdd(&hist[(kk >> shift) & 255], 1);
        }
        __syncthreads();
        if (tid < 64) {
            int L = tid;
            uint h0 = hist[4 * L], h1 = hist[4 * L + 1], h2 = hist[4 * L + 2],
                 h3 = hist[4 * L + 3];
            uint s3 = h3, s2 = h2 + s3, s1 = h1 + s2, s0 = h0 + s1;
            uint v = s0;
            for (int off = 1; off < 64; off <<= 1) {
                uint u = __shfl_down(v, off);
                if (L + off < 64) v += u;
            }
            uint above = v - s0;
            hist[4 * L] = s0 + above;
            hist[4 * L + 1] = s1 + above;
            hist[4 * L + 2] = s2 + above;
            hist[4 * L + 3] = s3 + above;
        }
        __syncthreads();
        if (tid < 256) {
            uint sb = hist[tid], sb1 = hist[tid + 1];
            if (sb >= rem && sb1 < rem) { s_b = (uint)tid; s_rem = rem - sb1; }
        }
        __syncthreads();
        prefix |= (s_b << shift);
        rem = s_rem;
        himask |= (0xFFu << shift);
        if (tid < 256) hist[tid] = 0;
        __syncthreads();
    }
    uint thr = prefix;
    uint m = rem;
    uint gcnt = 0, ecnt = 0, gflags = 0, eflags = 0;
    for (int j = 0; j < 2; j++) {
        uint kk = fkey(svals[tid + (j << 10)]);
        if (kk > thr) { gflags |= 1u << j; gcnt++; }
        else if (kk == thr) { eflags |= 1u << j; ecnt++; }
    }
    uint key = (gcnt << 16) | ecnt;
    uint v = key;
    for (int off = 1; off < 64; off <<= 1) {
        uint u = __shfl_up(v, off);
        if (lane >= off) v += u;
    }
    if (lane == 63) wsum[wid] = v;
    __syncthreads();
    if (tid < 16) {
        uint w0 = wsum[tid], w = w0;
        for (int off = 1; off < 16; off <<= 1) {
            uint u = __shfl_up(w, off);
            if ((int)tid >= off) w += u;
        }
        wsum[tid] = w - w0;
    }
    __syncthreads();
    uint excl = (v - key) + wsum[wid];
    uint gbase = excl >> 16, ebase = excl & 0xFFFFu;
    for (int j = 0; j < 2; j++) {
        bool gt = (gflags >> j) & 1u;
        bool eq = (eflags >> j) & 1u;
        if (gt || (eq && ebase < m)) {
            uint pos = gbase + min(ebase, m);
            int i = tid + (j << 10);
            int o = g * K1c + (int)pos;
            perm[o] = base + i;
            tval[o] = tanhf(svals[i]);
            mapL[i] = o;
        }
        gbase += gt ? 1u : 0u;
        ebase += eq ? 1u : 0u;
    }
    __syncthreads();
    int nbase = g * K1c;
    for (int j = 0; j < EPGc / 1024; j++) {
        int e = g * EPGc + tid + (j << 10);
        int ns = mapL[src[e] - base];
        int nt = mapL[tgt[e] - base];
        if (ns >= 0 && nt >= 0) {
            int p = atomicAdd(&wcL[nt - nbase], 1);
            col2[nt * SLAB + p] = ns;
        }
    }
    __syncthreads();
    wc2[nbase + tid] = wcL[tid];
}

// ---------------- topk2: ILP slab score + radix select ----------------
__global__ void __launch_bounds__(1024) topk2_kernel(const float* __restrict__ r,
                                                     const float* __restrict__ root,
                                                     const int* __restrict__ deg,
                                                     const int* __restrict__ col,
                                                     const float* __restrict__ brel,
                                                     int* __restrict__ perm,
                                                     float* __restrict__ tval) {
    __shared__ float svals[1024];
    __shared__ uint hist[257];
    __shared__ uint wsum[16];
    __shared__ uint s_b, s_rem;
    int g = blockIdx.x;
    int tid = threadIdx.x;
    int lane = tid & 63, wid = tid >> 6;
    float bv = brel[0];
    {
        int gi = g * K1c + tid;
        float acc = bv + root[gi];
        int e0 = gi * SLAB, dg = deg[gi];
        int4 c0 = *(const int4*)&col[e0];
        int4 c1 = *(const int4*)&col[e0 + 4];
        int idx[8] = {c0.x, c0.y, c0.z, c0.w, c1.x, c1.y, c1.z, c1.w};
#pragma unroll
        for (int j = 0; j < 8; j++)
            if (j < dg) acc += r[idx[j]];
        for (int e = e0 + 8; e < e0 + dg; e++) acc += r[col[e]];
        svals[tid] = acc;
    }
    if (tid == 256) hist[256] = 0;
    if (tid < 256) hist[tid] = 0;
    __syncthreads();

    uint prefix = 0, himask = 0, rem = (uint)K2c;
    for (int shift = 24; shift >= 0; shift -= 8) {
        {
            uint kk = fkey(svals[tid]);
            if ((kk & himask) == prefix) atomicAdd(&hist[(kk >> shift) & 255], 1);
        }
        __syncthreads();
        if (tid < 64) {
            int L = tid;
            uint h0 = hist[4 * L], h1 = hist[4 * L + 1], h2 = hist[4 * L + 2],
                 h3 = hist[4 * L + 3];
            uint s3 = h3, s2 = h2 + s3, s1 = h1 + s2, s0 = h0 + s1;
            uint v = s0;
            for (int off = 1; off < 64; off <<= 1) {
                uint u = __shfl_down(v, off);
                if (L + off < 64) v += u;
            }
            uint above = v - s0;
            hist[4 * L] = s0 + above;
            hist[4 * L + 1] = s1 + above;
            hist[4 * L + 2] = s2 + above;
            hist[4 * L + 3] = s3 + above;
        }
        __syncthreads();
        if (tid < 256) {
            uint sb = hist[tid], sb1 = hist[tid + 1];
            if (sb >= rem && sb1 < rem) { s_b = (uint)tid; s_rem = rem - sb1; }
        }
        __syncthreads();
        prefix |= (s_b << shift);
        rem = s_rem;
        himask |= (0xFFu << shift);
        if (tid < 256) hist[tid] = 0;
        __syncthreads();
    }
    uint thr = prefix;
    uint m = rem;

    uint kk = fkey(svals[tid]);
    bool gt = kk > thr, eq = kk == thr;
    uint key = (gt ? 0x10000u : 0u) | (eq ? 1u : 0u);
    uint v = key;
    for (int off = 1; off < 64; off <<= 1) {
        uint u = __shfl_up(v, off);
        if (lane >= off) v += u;
    }
    if (lane == 63) wsum[wid] = v;
    __syncthreads();
    if (tid < 16) {
        uint w0 = wsum[tid], w = w0;
        for (int off = 1; off < 16; off <<= 1) {
            uint u = __shfl_up(w, off);
            if ((int)tid >= off) w += u;
        }
        wsum[tid] = w - w0;
    }
    __syncthreads();
    uint excl = (v - key) + wsum[wid];
    uint gbase = excl >> 16, ebase = excl & 0xFFFFu;
    if (gt || (eq && ebase < m)) {
        uint pos = gbase + min(ebase, m);
        int o = g * K2c + (int)pos;
        perm[o] = g * K1c + tid;
        tval[o] = tanhf(svals[tid]);
    }
}

// -------- gather1: BN-apply + tanh-scale gather bf16 h1 -> h1pb (bf16) --------
__global__ void __launch_bounds__(256) gather1_kernel(
        const ushort* __restrict__ h1, const int* __restrict__ perm1,
        const float* __restrict__ tv1, const double* __restrict__ dsum,
        const double* __restrict__ dsq, const float* __restrict__ g,
        const float* __restrict__ b, ushort* __restrict__ h1pb) {
    __shared__ float sc[128], sh[128];
    if (threadIdx.x < 128) {
        int c = threadIdx.x;
        double m = dsum[c] / (double)Nn;
        double var = dsq[c] / (double)Nn - m * m;
        float s = g[c] * (float)(1.0 / sqrt(var + 1e-5));
        sc[c] = s; sh[c] = b[c] - (float)m * s;
    }
    __syncthreads();
    int t = blockIdx.x * 256 + threadIdx.x;
    int m = t >> 7, c = t & 127;
    float v = fmaxf(bf2f(h1[((size_t)perm1[m] << 7) + c]) * sc[c] + sh[c], 0.f);
    h1pb[t] = f2bf(v * tv1[m]);
}

// ---------------- fused: layer2 BN-apply + tanh-scale + pooled accumulate ----------------
__global__ void __launch_bounds__(256) pool_part_kernel(const ushort* __restrict__ h2,
                                                        const int* __restrict__ perm2,
                                                        const float* __restrict__ tv2,
                                                        const double* __restrict__ dsum,
                                                        const double* __restrict__ dsq,
                                                        const float* __restrict__ g,
                                                        const float* __restrict__ b,
                                                        float* __restrict__ pooled) {
    __shared__ float sc[256], sh[256];
    {
        int c = threadIdx.x;
        double m = dsum[c] / (double)N1c;
        double var = dsq[c] / (double)N1c - m * m;
        float s = g[c] * (float)(1.0 / sqrt(var + 1e-5));
        sc[c] = s; sh[c] = b[c] - (float)m * s;
    }
    __syncthreads();
    int gg = blockIdx.x, p = blockIdx.y, c = threadIdx.x;
    float s = 0.f;
    for (int j = 0; j < 64; j++) {
        int m = gg * K2c + p * 64 + j;
        int row = perm2[m];
        float v = fmaxf(bf2f(h2[((size_t)row << 8) + c]) * sc[c] + sh[c], 0.f);
        s += v * tv2[m];
    }
    atomicAdd(&pooled[gg * H2c + c], s);
}

__global__ void __launch_bounds__(256) pool_fin_kernel(const float* __restrict__ pooled,
                                                       const float* __restrict__ Wlin,
                                                       const float* __restrict__ blin,
                                                       float* __restrict__ out) {
    __shared__ float p0s[256], p1s[256];
    int g = blockIdx.x, c = threadIdx.x;
    float s = fmaxf(pooled[g * 256 + c] * (1.f / (float)K2c), 0.f);
    p0s[c] = s * Wlin[c * 2 + 0];
    p1s[c] = s * Wlin[c * 2 + 1];
    __syncthreads();
    for (int off = 128; off; off >>= 1) {
        if (c < off) { p0s[c] += p0s[c + off]; p1s[c] += p1s[c + off]; }
        __syncthreads();
    }
    if (c == 0) {
        float o0 = p0s[0] + blin[0], o1 = p1s[0] + blin[1];
        float m = fmaxf(o0, o1);
        float e0 = expf(o0 - m), e1 = expf(o1 - m);
        float inv = 1.f / (e0 + e1);
        out[g * 2 + 0] = e0 * inv;
        out[g * 2 + 1] = e1 * inv;
    }
}

extern "C" void kernel_launch(void* const* d_in, const int* in_sizes, int n_in,
                              void* d_out, int out_size, void* d_ws, size_t ws_size,
                              hipStream_t stream) {
    const float* x      = (const float*)d_in[0];
    const int*   ei     = (const int*)d_in[1];
    const int*   src    = ei;
    const int*   tgt    = ei + Ee;
    const float* W1l    = (const float*)d_in[3];
    const float* b1l    = (const float*)d_in[4];
    const float* W1r    = (const float*)d_in[5];
    const float* bn1g   = (const float*)d_in[6];
    const float* bn1b   = (const float*)d_in[7];
    const float* p1Wrel = (const float*)d_in[8];
    const float* p1brel = (const float*)d_in[9];
    const float* p1Wroot= (const float*)d_in[10];
    const float* W2l    = (const float*)d_in[11];
    const float* b2l    = (const float*)d_in[12];
    const float* W2r    = (const float*)d_in[13];
    const float* bn2g   = (const float*)d_in[14];
    const float* bn2b   = (const float*)d_in[15];
    const float* p2Wrel = (const float*)d_in[16];
    const float* p2brel = (const float*)d_in[17];
    const float* p2Wroot= (const float*)d_in[18];
    const float* Wlin   = (const float*)d_in[19];
    const float* blin   = (const float*)d_in[20];
    float* out = (float*)d_out;
    char* ws = (char*)d_ws;

    size_t o = 0;
    auto A = [&](size_t b) { size_t r = o; o += (b + 255) & ~(size_t)255; return r; };
    size_t oBIG1 = A((size_t)Nn * H1c * 2);        // h1 / h2 bf16
    size_t oBIG2 = A((size_t)Nn * INc * 4);        // xb + aggb1 bf16
    size_t oPB   = A((size_t)N1c * H1c * 4);       // h1pb + aggb2 bf16
    size_t oCol1 = A((size_t)Nn * SLAB * 4);
    size_t oCol2 = A((size_t)N1c * SLAB * 4);
    size_t oWc1  = A((size_t)Nn * 4);
    size_t oR1   = A((size_t)Nn * 4);
    size_t oRoot1= A((size_t)Nn * 4);
    size_t oPerm1= A((size_t)N1c * 4);
    size_t oTv1  = A((size_t)N1c * 4);
    size_t oWc2  = A((size_t)N1c * 4);
    size_t oR2   = A((size_t)N1c * 4);
    size_t oRoot2= A((size_t)N1c * 4);
    size_t oPerm2= A((size_t)N2c * 4);
    size_t oTv2  = A((size_t)N2c * 4);
    size_t oDst  = A(768 * 8);
    size_t oWt1l = A(8192 * 2);
    size_t oWt1r = A(8192 * 2);
    size_t oWt2l = A(32768 * 2);
    size_t oWt2r = A(32768 * 2);
    size_t oPool = A(Bg * H2c * 4);
    (void)ws_size; (void)in_sizes; (void)n_in; (void)out_size;

    ushort* h1   = (ushort*)(ws + oBIG1);
    ushort* h2   = (ushort*)(ws + oBIG1);
    ushort* xb   = (ushort*)(ws + oBIG2);
    ushort* aggb1= (ushort*)(ws + oBIG2 + (size_t)Nn * 64 * 2);
    ushort* h1pb = (ushort*)(ws + oPB);
    ushort* aggb2= (ushort*)(ws + oPB + (size_t)N1c * 128 * 2);
    int* col1    = (int*)(ws + oCol1);
    int* col2    = (int*)(ws + oCol2);
    int* wc1     = (int*)(ws + oWc1);
    float* r1    = (float*)(ws + oR1);
    float* root1 = (float*)(ws + oRoot1);
    int* perm1   = (int*)(ws + oPerm1);
    float* tv1   = (float*)(ws + oTv1);
    int* wc2     = (int*)(ws + oWc2);
    float* r2    = (float*)(ws + oR2);
    float* root2 = (float*)(ws + oRoot2);
    int* perm2   = (int*)(ws + oPerm2);
    float* tv2   = (float*)(ws + oTv2);
    double* dsum1= (double*)(ws + oDst);
    double* dsq1 = dsum1 + 128;
    double* dsum2= dsum1 + 256;
    double* dsq2 = dsum1 + 512;
    ushort* T1l  = (ushort*)(ws + oWt1l);
    ushort* T1r  = (ushort*)(ws + oWt1r);
    ushort* T2l  = (ushort*)(ws + oWt2l);
    ushort* T2r  = (ushort*)(ws + oWt2r);
    float* pooled= (float*)(ws + oPool);

    // 1. prep
    prep_kernel<<<(PREP_TOTAL + 255) / 256, 256, 0, stream>>>(
        x, W1l, W1r, W2l, W2r, T1l, T1r, T2l, T2r, xb, wc1, (int*)dsum1, (int*)pooled);

    // 2. layer1 slab CSR
    fill1_kernel<<<Ee / 256, 256, 0, stream>>>(src, tgt, wc1, col1);

    // 3-4. SAGEConv1 (+ fused BN1 stats)
    agg1_kernel<<<2048, 256, 0, stream>>>(xb, wc1, col1, aggb1);
    {
        dim3 g(Nn / 128, H1c / 64);
        gemm_mfma_kernel<INc, H1c><<<g, 256, 0, stream>>>(aggb1, xb, T1l, T1r, b1l, h1,
                                                          dsum1, dsq1);
    }

    // 5-6. score + topk1 (edge-parallel scores, fused map + layer2 fill)
    score_kernel<H1c><<<Nn / 4, 256, 0, stream>>>(h1, dsum1, dsq1, bn1g, bn1b, p1Wrel,
                                                  p1Wroot, r1, root1, Nn);
    topk1_kernel<<<Bg, 1024, 0, stream>>>(r1, root1, src, tgt, p1brel, perm1, tv1,
                                          wc2, col2);

    // 7. BN-apply gather (h1 -> h1pb)
    gather1_kernel<<<(N1c * H1c) / 256, 256, 0, stream>>>(h1, perm1, tv1, dsum1, dsq1,
                                                          bn1g, bn1b, h1pb);

    // 8-9. SAGEConv2 (+ fused BN2 stats)
    agg2_kernel<<<2048, 256, 0, stream>>>(h1pb, wc2, col2, aggb2);
    {
        dim3 g(N1c / 128, H2c / 64);
        gemm_mfma_kernel<H1c, H2c><<<g, 256, 0, stream>>>(aggb2, h1pb, T2l, T2r, b2l, h2,
                                                          dsum2, dsq2);
    }

    // 10-11. score + topk2
    score_kernel<H2c><<<N1c / 4, 256, 0, stream>>>(h2, dsum2, dsq2, bn2g, bn2b, p2Wrel,
                                                   p2Wroot, r2, root2, N1c);
    topk2_kernel<<<Bg, 1024, 0, stream>>>(r2, root2, wc2, col2, p2brel, perm2, tv2);

    // 12-13. fused BN-apply + tanh-scale + pool, then readout
    {
        dim3 g(Bg, K2c / 64);
        pool_part_kernel<<<g, 256, 0, stream>>>(h2, perm2, tv2, dsum2, dsq2, bn2g, bn2b,
                                                pooled);
    }
    pool_fin_kernel<<<Bg, 256, 0, stream>>>(pooled, Wlin, blin, out);
}